// Round 9
// baseline (86.645 us; speedup 1.0000x reference)
//
#include <hip/hip_runtime.h>

#define IO_DIM 64
#define WIDTH 16
#define HID 128
#define BS_ 1024                 // 64*16
#define NTH 256                  // 4 waves/block, 512 rows/block (R=2)

// ws layout v2 (floats):
//   wT [64][16]  at    0..1024)   : wT[k][j] = w[j][k]
//   uT [64][16]  at 1024..2048)   : uT[d][j] = u[j][d] / 16
//   bb [16]      at 2048..2064)
//   nuw[16]      at 2064..2080)   : -uw[j] / 16

__device__ __forceinline__ float fast_tanh(float x) {
    float e = __expf(2.0f * x);
    return 1.0f - __fdividef(2.0f, e + 1.0f);
}

__global__ __launch_bounds__(128) void cnf_prep(
    const float* __restrict__ t, const float* __restrict__ W1,
    const float* __restrict__ b1, const float* __restrict__ W2,
    const float* __restrict__ b2, const float* __restrict__ W3,
    const float* __restrict__ b3, float* __restrict__ ws)
{
    __shared__ float h1[HID];
    __shared__ float h2[HID];
    __shared__ float su[64], sw[64];
    const int tid = threadIdx.x;

    h1[tid] = tanhf(W1[tid] * t[0] + b1[tid]);
    __syncthreads();

    {
        float s = b2[tid];
        const float4* W2v = (const float4*)(W2 + tid * HID);
        #pragma unroll 8
        for (int k = 0; k < HID / 4; ++k) {
            float4 wv = W2v[k];
            s = fmaf(wv.x, h1[4 * k + 0], s);
            s = fmaf(wv.y, h1[4 * k + 1], s);
            s = fmaf(wv.z, h1[4 * k + 2], s);
            s = fmaf(wv.w, h1[4 * k + 3], s);
        }
        h2[tid] = tanhf(s);
    }
    __syncthreads();

    const int b = blockIdx.x;
    if (b < 16) {
        const int half = tid >> 6;   // 0 -> u, 1 -> w
        const int i = tid & 63;      // element index (d or k)
        const int row = half * BS_ + b * 64 + i;
        float s = b3[row];
        const float4* W3v = (const float4*)(W3 + row * HID);
        #pragma unroll 8
        for (int k = 0; k < HID / 4; ++k) {
            float4 wv = W3v[k];
            s = fmaf(wv.x, h2[4 * k + 0], s);
            s = fmaf(wv.y, h2[4 * k + 1], s);
            s = fmaf(wv.z, h2[4 * k + 2], s);
            s = fmaf(wv.w, h2[4 * k + 3], s);
        }
        if (half == 0) {
            ws[1024 + i * 16 + b] = s * (1.0f / WIDTH);   // uT[d][j], scale folded
            su[i] = s;
        } else {
            ws[i * 16 + b] = s;                           // wT[k][j]
            sw[i] = s;
        }
        __syncthreads();
        if (tid < 64) {
            float p = su[tid] * sw[tid];
            #pragma unroll
            for (int m = 32; m >= 1; m >>= 1) p += __shfl_xor(p, m, 64);
            if (tid == 0) ws[2064 + b] = -p * (1.0f / WIDTH);   // nuw[b]
        }
    } else {
        if (tid < WIDTH) {
            const int row = 2 * BS_ + tid;
            float s = b3[row];
            const float4* W3v = (const float4*)(W3 + row * HID);
            #pragma unroll 8
            for (int k = 0; k < HID / 4; ++k) {
                float4 wv = W3v[k];
                s = fmaf(wv.x, h2[4 * k + 0], s);
                s = fmaf(wv.y, h2[4 * k + 1], s);
                s = fmaf(wv.z, h2[4 * k + 2], s);
                s = fmaf(wv.w, h2[4 * k + 3], s);
            }
            ws[2048 + tid] = s;   // bb
        }
    }
}

__global__ __launch_bounds__(NTH, 4) void cnf_main(
    const float* __restrict__ z, const float* __restrict__ ws,
    float* __restrict__ dz, float* __restrict__ dlog, int n)
{
    // Wave-private 8 KB transpose slices (proven conflict-free, full-line
    // stores). Zero barriers: same-wave DS ops are in-order (rounds 5-8).
    __shared__ __align__(16) float4 slice[4][64][8];

    const int tid = threadIdx.x;
    const int wv  = tid >> 6;
    const int l   = tid & 63;
    const int wbase = blockIdx.x * (NTH * 2) + wv * 128;  // wave owns 128 rows
    const int r0 = wbase + l;
    const int r1 = wbase + 64 + l;
    const int r0c = min(r0, n - 1);
    const int r1c = min(r1, n - 1);

    const float4* z0 = (const float4*)z + (size_t)r0c * 16;
    const float4* z1 = (const float4*)z + (size_t)r1c * 16;

    // phase 1: a[j] = bb[j] + sum_k z[k]*wT[k][j], two rows sharing each
    // weight fetch. Outer half-loop kept as a runtime loop (small I$);
    // inner kc unrolled so za/zb stay statically indexed (regs).
    float a0[WIDTH], a1[WIDTH];
    #pragma unroll
    for (int j = 0; j < WIDTH; ++j) { a0[j] = ws[2048 + j]; a1[j] = a0[j]; }

    #pragma unroll 1
    for (int half = 0; half < 2; ++half) {
        float4 za[8], zb[8];
        #pragma unroll
        for (int i = 0; i < 8; ++i) za[i] = z0[half * 8 + i];
        #pragma unroll
        for (int i = 0; i < 8; ++i) zb[i] = z1[half * 8 + i];
        const float* wh = ws + half * 512;
        #pragma unroll
        for (int kc = 0; kc < 8; ++kc) {
            const float* wk = wh + kc * 64;
            const float4 x = za[kc], y = zb[kc];
            #pragma unroll
            for (int j = 0; j < WIDTH; ++j) {
                const float w0 = wk[j];
                a0[j] = fmaf(x.x, w0, a0[j]);  a1[j] = fmaf(y.x, w0, a1[j]);
            }
            #pragma unroll
            for (int j = 0; j < WIDTH; ++j) {
                const float w1 = wk[16 + j];
                a0[j] = fmaf(x.y, w1, a0[j]);  a1[j] = fmaf(y.y, w1, a1[j]);
            }
            #pragma unroll
            for (int j = 0; j < WIDTH; ++j) {
                const float w2 = wk[32 + j];
                a0[j] = fmaf(x.z, w2, a0[j]);  a1[j] = fmaf(y.z, w2, a1[j]);
            }
            #pragma unroll
            for (int j = 0; j < WIDTH; ++j) {
                const float w3 = wk[48 + j];
                a0[j] = fmaf(x.w, w3, a0[j]);  a1[j] = fmaf(y.w, w3, a1[j]);
            }
        }
    }

    // tanh + trace for both rows
    float tr0 = 0.0f, tr1 = 0.0f;
    #pragma unroll
    for (int j = 0; j < WIDTH; ++j) {
        const float nw = ws[2064 + j];
        float t0 = fast_tanh(a0[j]);
        float t1 = fast_tanh(a1[j]);
        a0[j] = t0;  a1[j] = t1;
        tr0 = fmaf(1.0f - t0 * t0, nw, tr0);
        tr1 = fmaf(1.0f - t1 * t1, nw, tr1);
    }
    if (r0 < n) dlog[r0] = tr0;
    if (r1 < n) dlog[r1] = tr1;

    // phase 2: dz = th @ uT in two 128-B halves; both rows share each uT
    // fetch. r0's half goes through the slice first; r1's is kept in regs
    // (statically indexed) and follows through the same slice.
    float4* dzv = (float4*)dz;

    #pragma unroll 1
    for (int h = 0; h < 2; ++h) {
        float4 keep[8];
        #pragma unroll
        for (int c = 0; c < 8; ++c) {
            const float* uc = ws + 1024 + (h * 32 + c * 4) * 16;
            float4 o0 = make_float4(0.f, 0.f, 0.f, 0.f);
            float4 o1 = make_float4(0.f, 0.f, 0.f, 0.f);
            #pragma unroll
            for (int j = 0; j < WIDTH; ++j) {
                const float u0 = uc[j], u1 = uc[16 + j];
                const float u2 = uc[32 + j], u3 = uc[48 + j];
                const float t0 = a0[j], t1 = a1[j];
                o0.x = fmaf(t0, u0, o0.x);  o1.x = fmaf(t1, u0, o1.x);
                o0.y = fmaf(t0, u1, o0.y);  o1.y = fmaf(t1, u1, o1.y);
                o0.z = fmaf(t0, u2, o0.z);  o1.z = fmaf(t1, u2, o1.z);
                o0.w = fmaf(t0, u3, o0.w);  o1.w = fmaf(t1, u3, o1.w);
            }
            slice[wv][l][c ^ (l & 7)] = o0;
            keep[c] = o1;
        }
        // transposed store r0: 8 instrs, each 8 consecutive rows x 128 B line
        #pragma unroll
        for (int s = 0; s < 8; ++s) {
            const int r = 8 * s + (l >> 3);
            const float4 v = slice[wv][r][(l & 7) ^ (r & 7)];
            const int grow = wbase + r;
            if (grow < n)
                dzv[(size_t)grow * 16 + h * 8 + (l & 7)] = v;
        }
        // r1 half through the same slice (same-wave in-order, no barrier)
        #pragma unroll
        for (int c = 0; c < 8; ++c)
            slice[wv][l][c ^ (l & 7)] = keep[c];
        #pragma unroll
        for (int s = 0; s < 8; ++s) {
            const int r = 8 * s + (l >> 3);
            const float4 v = slice[wv][r][(l & 7) ^ (r & 7)];
            const int grow = wbase + 64 + r;
            if (grow < n)
                dzv[(size_t)grow * 16 + h * 8 + (l & 7)] = v;
        }
    }
}

extern "C" void kernel_launch(void* const* d_in, const int* in_sizes, int n_in,
                              void* d_out, int out_size, void* d_ws, size_t ws_size,
                              hipStream_t stream) {
    const float* t  = (const float*)d_in[0];
    const float* z  = (const float*)d_in[1];
    const float* W1 = (const float*)d_in[2];
    const float* b1 = (const float*)d_in[3];
    const float* W2 = (const float*)d_in[4];
    const float* b2 = (const float*)d_in[5];
    const float* W3 = (const float*)d_in[6];
    const float* b3 = (const float*)d_in[7];

    const int n = in_sizes[1] / IO_DIM;   // 500000
    float* ws   = (float*)d_ws;
    float* out  = (float*)d_out;
    float* dz   = out;
    float* dlog = out + (size_t)n * IO_DIM;

    cnf_prep<<<17, 128, 0, stream>>>(t, W1, b1, W2, b2, W3, b3, ws);

    const int rows_per_block = NTH * 2;
    const int grid = (n + rows_per_block - 1) / rows_per_block;
    cnf_main<<<grid, NTH, 0, stream>>>(z, ws, dz, dlog, n);
}

// Round 10
// 80.533 us; speedup vs baseline: 1.0759x; 1.0759x over previous
//
#include <hip/hip_runtime.h>

#define IO_DIM 64
#define WIDTH 16
#define HID 128
#define BS_ 1024                 // 64*16
#define NTH 128                  // 2 waves/block

// ws layout v2 (floats):
//   wT [64][16]  at    0..1024)   : wT[k][j] = w[j][k]
//   uT [64][16]  at 1024..2048)   : uT[d][j] = u[j][d] / 16
//   bb [16]      at 2048..2064)
//   nuw[16]      at 2064..2080)   : -uw[j] / 16

__device__ __forceinline__ float fast_tanh(float x) {
    float e = __expf(2.0f * x);
    return 1.0f - __fdividef(2.0f, e + 1.0f);
}

__global__ __launch_bounds__(128) void cnf_prep(
    const float* __restrict__ t, const float* __restrict__ W1,
    const float* __restrict__ b1, const float* __restrict__ W2,
    const float* __restrict__ b2, const float* __restrict__ W3,
    const float* __restrict__ b3, float* __restrict__ ws)
{
    __shared__ float h1[HID];
    __shared__ float h2[HID];
    __shared__ float su[64], sw[64];
    const int tid = threadIdx.x;

    h1[tid] = tanhf(W1[tid] * t[0] + b1[tid]);
    __syncthreads();

    {
        float s = b2[tid];
        const float4* W2v = (const float4*)(W2 + tid * HID);
        #pragma unroll 8
        for (int k = 0; k < HID / 4; ++k) {
            float4 wv = W2v[k];
            s = fmaf(wv.x, h1[4 * k + 0], s);
            s = fmaf(wv.y, h1[4 * k + 1], s);
            s = fmaf(wv.z, h1[4 * k + 2], s);
            s = fmaf(wv.w, h1[4 * k + 3], s);
        }
        h2[tid] = tanhf(s);
    }
    __syncthreads();

    const int b = blockIdx.x;
    if (b < 16) {
        const int half = tid >> 6;   // 0 -> u, 1 -> w
        const int i = tid & 63;      // element index (d or k)
        const int row = half * BS_ + b * 64 + i;
        float s = b3[row];
        const float4* W3v = (const float4*)(W3 + row * HID);
        #pragma unroll 8
        for (int k = 0; k < HID / 4; ++k) {
            float4 wv = W3v[k];
            s = fmaf(wv.x, h2[4 * k + 0], s);
            s = fmaf(wv.y, h2[4 * k + 1], s);
            s = fmaf(wv.z, h2[4 * k + 2], s);
            s = fmaf(wv.w, h2[4 * k + 3], s);
        }
        if (half == 0) {
            ws[1024 + i * 16 + b] = s * (1.0f / WIDTH);   // uT[d][j], scale folded
            su[i] = s;
        } else {
            ws[i * 16 + b] = s;                           // wT[k][j]
            sw[i] = s;
        }
        __syncthreads();
        if (tid < 64) {
            float p = su[tid] * sw[tid];
            #pragma unroll
            for (int m = 32; m >= 1; m >>= 1) p += __shfl_xor(p, m, 64);
            if (tid == 0) ws[2064 + b] = -p * (1.0f / WIDTH);   // nuw[b]
        }
    } else {
        if (tid < WIDTH) {
            const int row = 2 * BS_ + tid;
            float s = b3[row];
            const float4* W3v = (const float4*)(W3 + row * HID);
            #pragma unroll 8
            for (int k = 0; k < HID / 4; ++k) {
                float4 wv = W3v[k];
                s = fmaf(wv.x, h2[4 * k + 0], s);
                s = fmaf(wv.y, h2[4 * k + 1], s);
                s = fmaf(wv.z, h2[4 * k + 2], s);
                s = fmaf(wv.w, h2[4 * k + 3], s);
            }
            ws[2048 + tid] = s;   // bb
        }
    }
}

__global__ __launch_bounds__(NTH) void cnf_main(
    const float* __restrict__ z, const float* __restrict__ ws,
    float* __restrict__ dz, float* __restrict__ dlog, int n)
{
    // Wave-private 16 KB tiles (2 waves): z staging in phase 1, dz transpose
    // in phase 2. ZERO barriers (same-wave DS ops in-order, rounds 5-8).
    __shared__ __align__(16) float4 slice[2][64][16];   // 32 KB

    const int tid = threadIdx.x;
    const int wv  = tid >> 6;
    const int l   = tid & 63;
    const int wbase = blockIdx.x * NTH + wv * 64;       // wave owns 64 rows
    const int row = wbase + l;
    const int n16 = n * 16;

    // stage z: 16 fully-coalesced 1 KB loads -> swizzled ds_write.
    // instr i covers chunks i*64+l -> tile row i*4+(l>>4), col l&15.
    const float4* zv4 = (const float4*)z;
    #pragma unroll
    for (int i = 0; i < 16; ++i) {
        int g = wbase * 16 + i * 64 + l;
        g = min(g, n16 - 1);              // clamp on last tile
        const float4 v = zv4[g];
        const int r = i * 4 + (l >> 4);
        slice[wv][r][(l & 15) ^ (r & 15)] = v;   // 8 words/bank floor
    }

    // phase 1: a[j] = bb[j] + sum_k z[k] * wT[k][j]  (weights via uniform s_load)
    float a[WIDTH];
    #pragma unroll
    for (int j = 0; j < WIDTH; ++j) a[j] = ws[2048 + j];

    #pragma unroll
    for (int k4 = 0; k4 < 16; ++k4) {
        const float4 zv = slice[wv][l][k4 ^ (l & 15)];   // own row, swizzle-matched
        const float* wk = ws + k4 * 64;                  // wT rows 4k4..4k4+3
        #pragma unroll
        for (int j = 0; j < WIDTH; ++j) a[j] = fmaf(zv.x, wk[j],      a[j]);
        #pragma unroll
        for (int j = 0; j < WIDTH; ++j) a[j] = fmaf(zv.y, wk[16 + j], a[j]);
        #pragma unroll
        for (int j = 0; j < WIDTH; ++j) a[j] = fmaf(zv.z, wk[32 + j], a[j]);
        #pragma unroll
        for (int j = 0; j < WIDTH; ++j) a[j] = fmaf(zv.w, wk[48 + j], a[j]);
    }

    // tanh + trace
    float tr = 0.0f;
    #pragma unroll
    for (int j = 0; j < WIDTH; ++j) {
        float th = fast_tanh(a[j]);
        a[j] = th;
        tr = fmaf(1.0f - th * th, ws[2064 + j], tr);
    }
    if (row < n) dlog[row] = tr;

    // phase 2: dz = th @ uT in two 128-B halves through cols 0..7 of the tile.
    // Safe reuse: every lane's phase-1 ds_reads precede these ds_writes in
    // wave program order, and same-wave DS is in-order.
    const float* uT = ws + 1024;
    float4* dzv = (float4*)dz;

    #pragma unroll
    for (int h = 0; h < 2; ++h) {
        #pragma unroll
        for (int c = 0; c < 8; ++c) {
            const int d0 = h * 32 + c * 4;
            float4 o = make_float4(0.f, 0.f, 0.f, 0.f);
            #pragma unroll
            for (int j = 0; j < WIDTH; ++j) {
                const float th = a[j];
                o.x = fmaf(th, uT[(d0 + 0) * 16 + j], o.x);
                o.y = fmaf(th, uT[(d0 + 1) * 16 + j], o.y);
                o.z = fmaf(th, uT[(d0 + 2) * 16 + j], o.z);
                o.w = fmaf(th, uT[(d0 + 3) * 16 + j], o.w);
            }
            slice[wv][l][c ^ (l & 7)] = o;    // stage own row's 128-B half
        }
        // transposed store: 8 instrs, each 8 consecutive rows x full 128-B line
        #pragma unroll
        for (int s = 0; s < 8; ++s) {
            const int r = 8 * s + (l >> 3);
            const float4 v = slice[wv][r][(l & 7) ^ (r & 7)];
            const int grow = wbase + r;
            if (grow < n)
                dzv[(size_t)grow * 16 + h * 8 + (l & 7)] = v;
        }
    }
}

extern "C" void kernel_launch(void* const* d_in, const int* in_sizes, int n_in,
                              void* d_out, int out_size, void* d_ws, size_t ws_size,
                              hipStream_t stream) {
    const float* t  = (const float*)d_in[0];
    const float* z  = (const float*)d_in[1];
    const float* W1 = (const float*)d_in[2];
    const float* b1 = (const float*)d_in[3];
    const float* W2 = (const float*)d_in[4];
    const float* b2 = (const float*)d_in[5];
    const float* W3 = (const float*)d_in[6];
    const float* b3 = (const float*)d_in[7];

    const int n = in_sizes[1] / IO_DIM;   // 500000
    float* ws   = (float*)d_ws;
    float* out  = (float*)d_out;
    float* dz   = out;
    float* dlog = out + (size_t)n * IO_DIM;

    cnf_prep<<<17, 128, 0, stream>>>(t, W1, b1, W2, b2, W3, b3, ws);

    const int grid = (n + NTH - 1) / NTH;
    cnf_main<<<grid, NTH, 0, stream>>>(z, ws, dz, dlog, n);
}

// Round 11
// 58.952 us; speedup vs baseline: 1.4698x; 1.3661x over previous
//
#include <hip/hip_runtime.h>

#define IO_DIM 64
#define WIDTH 16
#define HID 128
#define BS_ 1024                 // 64*16
#define NTH 128                  // 2 waves/block

// ws layout v2 (floats):
//   wT [64][16]  at    0..1024)   : wT[k][j] = w[j][k]
//   uT [64][16]  at 1024..2048)   : uT[d][j] = u[j][d] / 16
//   bb [16]      at 2048..2064)
//   nuw[16]      at 2064..2080)   : -uw[j] / 16

typedef __attribute__((ext_vector_type(4))) float f32x4;
typedef __attribute__((ext_vector_type(8))) short bf16x8;

union U4 { unsigned u[4]; bf16x8 v; };

__device__ __forceinline__ unsigned cvt_pk_bf16(float lo, float hi) {
    unsigned r;
    asm("v_cvt_pk_bf16_f32 %0, %1, %2" : "=v"(r) : "v"(lo), "v"(hi));
    return r;
}

__device__ __forceinline__ float fast_tanh(float x) {
    float e = __expf(2.0f * x);
    return 1.0f - __fdividef(2.0f, e + 1.0f);
}

// split 8 f32 into bf16 hi (RTNE) + bf16 lo (residual) fragments
__device__ __forceinline__ void split8(const float* x, bf16x8& hi, bf16x8& lo) {
    U4 H, L;
    #pragma unroll
    for (int i = 0; i < 4; ++i) {
        unsigned h = cvt_pk_bf16(x[2 * i], x[2 * i + 1]);
        float h0 = __uint_as_float(h << 16);
        float h1 = __uint_as_float(h & 0xffff0000u);
        H.u[i] = h;
        L.u[i] = cvt_pk_bf16(x[2 * i] - h0, x[2 * i + 1] - h1);
    }
    hi = H.v; lo = L.v;
}

__global__ __launch_bounds__(128) void cnf_prep(
    const float* __restrict__ t, const float* __restrict__ W1,
    const float* __restrict__ b1, const float* __restrict__ W2,
    const float* __restrict__ b2, const float* __restrict__ W3,
    const float* __restrict__ b3, float* __restrict__ ws)
{
    __shared__ float h1[HID];
    __shared__ float h2[HID];
    __shared__ float su[64], sw[64];
    const int tid = threadIdx.x;

    h1[tid] = tanhf(W1[tid] * t[0] + b1[tid]);
    __syncthreads();

    {
        float s = b2[tid];
        const float4* W2v = (const float4*)(W2 + tid * HID);
        #pragma unroll 8
        for (int k = 0; k < HID / 4; ++k) {
            float4 wv = W2v[k];
            s = fmaf(wv.x, h1[4 * k + 0], s);
            s = fmaf(wv.y, h1[4 * k + 1], s);
            s = fmaf(wv.z, h1[4 * k + 2], s);
            s = fmaf(wv.w, h1[4 * k + 3], s);
        }
        h2[tid] = tanhf(s);
    }
    __syncthreads();

    const int b = blockIdx.x;
    if (b < 16) {
        const int half = tid >> 6;   // 0 -> u, 1 -> w
        const int i = tid & 63;      // element index (d or k)
        const int row = half * BS_ + b * 64 + i;
        float s = b3[row];
        const float4* W3v = (const float4*)(W3 + row * HID);
        #pragma unroll 8
        for (int k = 0; k < HID / 4; ++k) {
            float4 wv = W3v[k];
            s = fmaf(wv.x, h2[4 * k + 0], s);
            s = fmaf(wv.y, h2[4 * k + 1], s);
            s = fmaf(wv.z, h2[4 * k + 2], s);
            s = fmaf(wv.w, h2[4 * k + 3], s);
        }
        if (half == 0) {
            ws[1024 + i * 16 + b] = s * (1.0f / WIDTH);   // uT[d][j], scale folded
            su[i] = s;
        } else {
            ws[i * 16 + b] = s;                           // wT[k][j]
            sw[i] = s;
        }
        __syncthreads();
        if (tid < 64) {
            float p = su[tid] * sw[tid];
            #pragma unroll
            for (int m = 32; m >= 1; m >>= 1) p += __shfl_xor(p, m, 64);
            if (tid == 0) ws[2064 + b] = -p * (1.0f / WIDTH);   // nuw[b]
        }
    } else {
        if (tid < WIDTH) {
            const int row = 2 * BS_ + tid;
            float s = b3[row];
            const float4* W3v = (const float4*)(W3 + row * HID);
            #pragma unroll 8
            for (int k = 0; k < HID / 4; ++k) {
                float4 wv = W3v[k];
                s = fmaf(wv.x, h2[4 * k + 0], s);
                s = fmaf(wv.y, h2[4 * k + 1], s);
                s = fmaf(wv.z, h2[4 * k + 2], s);
                s = fmaf(wv.w, h2[4 * k + 3], s);
            }
            ws[2048 + tid] = s;   // bb
        }
    }
}

// MFMA main kernel. Per wave: 64 rows.
// phase1 (swapped): a^T[j][r] = sum_k w[j][k] z[r][k] + bb[j]
//   A = w fragments (pinned VGPR, hi/lo), B = z fragments (staged LDS, hi/lo),
//   3 MFMAs per K-half (drop lo*lo), 2 K-halves.
// phase2: dz^T[d][r] = sum_j u'[d][j] th[j][r]
//   A = u' fragments (pinned, hi/lo, j>=16 zero), B = th (cvt_pk + 4 shfl).
__global__ __launch_bounds__(NTH) void cnf_main(
    const float* __restrict__ z, const float* __restrict__ ws,
    float* __restrict__ dz, float* __restrict__ dlog, int n)
{
    // wave-private z staging, half-tile (cols 0-31 then 32-63): 8 KB/wave.
    // ZERO barriers: same-wave DS ops are in-order (validated rounds 5-8).
    __shared__ __align__(16) float4 zbuf[2][64][8];

    const int tid = threadIdx.x;
    const int wv  = tid >> 6;
    const int l   = tid & 63;
    const int q   = l >> 4;          // lane quadrant
    const int r15 = l & 15;
    const int wbase = blockIdx.x * NTH + wv * 64;

    // ---- pinned weight fragments (loaded once) ----
    // w: A-frag rows j=r15, k = h*32 + q*8 + e
    bf16x8 whi[2], wlo[2];
    #pragma unroll
    for (int h = 0; h < 2; ++h) {
        float w8[8];
        #pragma unroll
        for (int e = 0; e < 8; ++e)
            w8[e] = ws[(h * 32 + q * 8 + e) * 16 + r15];
        split8(w8, whi[h], wlo[h]);
    }
    // u': A-frag rows d = dt*16 + r15, k = j = q*8 + e (zero for j>=16)
    bf16x8 uhi[4], ulo[4];
    #pragma unroll
    for (int dt = 0; dt < 4; ++dt) {
        float u8[8];
        #pragma unroll
        for (int e = 0; e < 8; ++e)
            u8[e] = (q < 2) ? ws[1024 + (dt * 16 + r15) * 16 + q * 8 + e] : 0.0f;
        split8(u8, uhi[dt], ulo[dt]);
    }
    f32x4 bbv; float nuwv[4];
    #pragma unroll
    for (int rr = 0; rr < 4; ++rr) {
        bbv[rr]  = ws[2048 + q * 4 + rr];   // bb[j], j = 4q+rr
        nuwv[rr] = ws[2064 + q * 4 + rr];
    }

    const int n16 = n * 16;
    const float4* zg = (const float4*)z;
    float4* myz = &zbuf[wv][0][0];
    const int wslot = (l & 7) ^ (l >> 3);   // staging swizzle (bank-uniform)

    f32x4 acc[4];
    #pragma unroll
    for (int g = 0; g < 4; ++g) acc[g] = bbv;

    // ---- phase 1: two K-halves through the 8 KB slice ----
    #pragma unroll
    for (int h = 0; h < 2; ++h) {
        // stage: 8 instrs, each 8 rows x 128 B (full lines, 8 segments)
        #pragma unroll
        for (int i = 0; i < 8; ++i) {
            const int rowl = 8 * i + (l >> 3);
            int gi = (wbase + rowl) * 16 + h * 8 + (l & 7);
            gi = min(gi, n16 - 1);
            myz[rowl * 8 + wslot] = zg[gi];
        }
        // consume: per 16-row group, B-frag = z[r][h*32 + q*8 + 0..7]
        #pragma unroll
        for (int g = 0; g < 4; ++g) {
            const int row = g * 16 + r15;
            const float4 zA = myz[row * 8 + ((2 * q)     ^ (l & 7))];
            const float4 zB = myz[row * 8 + ((2 * q + 1) ^ (l & 7))];
            float z8[8] = {zA.x, zA.y, zA.z, zA.w, zB.x, zB.y, zB.z, zB.w};
            bf16x8 zhi, zlo; split8(z8, zhi, zlo);
            acc[g] = __builtin_amdgcn_mfma_f32_16x16x32_bf16(whi[h], zhi, acc[g], 0, 0, 0);
            acc[g] = __builtin_amdgcn_mfma_f32_16x16x32_bf16(wlo[h], zhi, acc[g], 0, 0, 0);
            acc[g] = __builtin_amdgcn_mfma_f32_16x16x32_bf16(whi[h], zlo, acc[g], 0, 0, 0);
        }
    }

    // ---- phase 2 + outputs, per 16-row group ----
    float trs[4];
    const int sbase = ((2 * q) & 3) * 16 + r15;   // q>=2: dummy (masked below)
    float4* dzv = (float4*)dz;

    #pragma unroll
    for (int g = 0; g < 4; ++g) {
        const float t0 = fast_tanh(acc[g][0]);
        const float t1 = fast_tanh(acc[g][1]);
        const float t2 = fast_tanh(acc[g][2]);
        const float t3 = fast_tanh(acc[g][3]);

        float tr = (1.0f - t0 * t0) * nuwv[0];
        tr = fmaf(1.0f - t1 * t1, nuwv[1], tr);
        tr = fmaf(1.0f - t2 * t2, nuwv[2], tr);
        tr = fmaf(1.0f - t3 * t3, nuwv[3], tr);
        tr += __shfl_xor(tr, 16);
        tr += __shfl_xor(tr, 32);
        trs[g] = tr;

        // th -> B-frag: lane needs th[j = q*8+e][r15] from quadrants 2q, 2q+1
        const int pk01 = (int)cvt_pk_bf16(t0, t1);
        const int pk23 = (int)cvt_pk_bf16(t2, t3);
        const int w0 = __shfl(pk01, sbase);
        const int w1 = __shfl(pk23, sbase);
        const int w2 = __shfl(pk01, sbase + 16);
        const int w3 = __shfl(pk23, sbase + 16);
        const bool act = (q < 2);
        U4 B;
        B.u[0] = act ? (unsigned)w0 : 0u;
        B.u[1] = act ? (unsigned)w1 : 0u;
        B.u[2] = act ? (unsigned)w2 : 0u;
        B.u[3] = act ? (unsigned)w3 : 0u;
        const bf16x8 b2 = B.v;

        f32x4 o[4];
        #pragma unroll
        for (int dt = 0; dt < 4; ++dt) {
            f32x4 zz = {0.f, 0.f, 0.f, 0.f};
            zz    = __builtin_amdgcn_mfma_f32_16x16x32_bf16(ulo[dt], b2, zz, 0, 0, 0);
            o[dt] = __builtin_amdgcn_mfma_f32_16x16x32_bf16(uhi[dt], b2, zz, 0, 0, 0);
        }
        // stores: lane holds dz[row = wbase+g*16+r15][d = dt*16+4q .. +3]
        const int grow = wbase + g * 16 + r15;
        if (grow < n) {
            #pragma unroll
            for (int dt = 0; dt < 4; ++dt) {
                float4 s = make_float4(o[dt][0], o[dt][1], o[dt][2], o[dt][3]);
                dzv[(size_t)grow * 16 + dt * 4 + q] = s;
            }
        }
    }

    // dlog: lane l -> row wbase + l = group q, in-group row r15
    float trf = trs[0];
    trf = (q == 1) ? trs[1] : trf;
    trf = (q == 2) ? trs[2] : trf;
    trf = (q == 3) ? trs[3] : trf;
    if (wbase + l < n) dlog[wbase + l] = trf;
}

extern "C" void kernel_launch(void* const* d_in, const int* in_sizes, int n_in,
                              void* d_out, int out_size, void* d_ws, size_t ws_size,
                              hipStream_t stream) {
    const float* t  = (const float*)d_in[0];
    const float* z  = (const float*)d_in[1];
    const float* W1 = (const float*)d_in[2];
    const float* b1 = (const float*)d_in[3];
    const float* W2 = (const float*)d_in[4];
    const float* b2 = (const float*)d_in[5];
    const float* W3 = (const float*)d_in[6];
    const float* b3 = (const float*)d_in[7];

    const int n = in_sizes[1] / IO_DIM;   // 500000
    float* ws   = (float*)d_ws;
    float* out  = (float*)d_out;
    float* dzp  = out;
    float* dlog = out + (size_t)n * IO_DIM;

    cnf_prep<<<17, 128, 0, stream>>>(t, W1, b1, W2, b2, W3, b3, ws);

    const int grid = (n + NTH - 1) / NTH;
    cnf_main<<<grid, NTH, 0, stream>>>(z, ws, dzp, dlog, n);
}